// Round 1
// baseline (374.954 us; speedup 1.0000x reference)
//
#include <hip/hip_runtime.h>

typedef __bf16 bf16;
typedef __bf16 bf16x8 __attribute__((ext_vector_type(8)));
typedef __bf16 bf16x4 __attribute__((ext_vector_type(4)));
typedef float  f32x4  __attribute__((ext_vector_type(4)));

#define BN_EPS 1e-5f

// Fragment-linear offset for MFMA B-operand matrix [N][K] (16x16x32 tiles):
// tile = (k/32)*ntiles + n/16 ; within tile: lane = ((k%32)/8)*16 + n%16, elem = k%8
__device__ __host__ __forceinline__ size_t frag_off(int n, int k, int ntiles) {
  return ((size_t)((k >> 5) * ntiles + (n >> 4)) << 9)
       + (size_t)((((k >> 3) & 3) << 4) + (n & 15)) * 8 + (k & 7);
}

// ---------------- prep kernels: fold BN, cast to bf16, swizzle to fragment layout ----------------

__global__ void prep_w1main(const float* __restrict__ l1w, const float* __restrict__ l1g, const float* __restrict__ l1v,
                            const float* __restrict__ g1w, const float* __restrict__ g1g, const float* __restrict__ g1v,
                            bf16* __restrict__ W1f) {
  int gid = blockIdx.x * blockDim.x + threadIdx.x;   // 512*1024
  int n = gid >> 10, k = gid & 1023;
  float s, w;
  if (n < 256) { s = l1g[n] * rsqrtf(l1v[n] + BN_EPS); w = l1w[(size_t)n * 1024 + k]; }
  else { int nn = n - 256; s = g1g[nn] * rsqrtf(g1v[nn] + BN_EPS); w = g1w[(size_t)nn * 1024 + k]; }
  W1f[frag_off(n, k, 32)] = (bf16)(w * s);
}

// tail columns 1024..1087 of W1cat = (s*W1) @ [cw | cb | 0], plus b1cat
__global__ void prep_w1tail(const float* __restrict__ l1w, const float* __restrict__ l1b, const float* __restrict__ l1g,
                            const float* __restrict__ l1be, const float* __restrict__ l1m, const float* __restrict__ l1v,
                            const float* __restrict__ g1w, const float* __restrict__ g1b, const float* __restrict__ g1g,
                            const float* __restrict__ g1be, const float* __restrict__ g1m, const float* __restrict__ g1v,
                            const float* __restrict__ cw, const float* __restrict__ cb,
                            bf16* __restrict__ W1f, float* __restrict__ b1cat) {
  int gid = blockIdx.x * blockDim.x + threadIdx.x;   // 512*64
  int n = gid >> 6, kc = gid & 63;
  const float* wrow; float s, bb, mm, be;
  if (n < 256) { s = l1g[n] * rsqrtf(l1v[n] + BN_EPS); wrow = l1w + (size_t)n * 1024;
                 bb = l1b[n]; mm = l1m[n]; be = l1be[n]; }
  else { int nn = n - 256; s = g1g[nn] * rsqrtf(g1v[nn] + BN_EPS); wrow = g1w + (size_t)nn * 1024;
         bb = g1b[nn]; mm = g1m[nn]; be = g1be[nn]; }
  float val = 0.f;
  if (kc < 49) {
    for (int j = 0; j < 1024; ++j) {
      float cv = (kc < 48) ? cw[(size_t)j * 48 + kc] : cb[j];
      val += wrow[j] * cv;
    }
    val *= s;
  }
  W1f[frag_off(n, 1024 + kc, 32)] = (bf16)val;
  if (kc == 0) b1cat[n] = s * (bb - mm) + be;
}

__global__ void prep_w2(const float* __restrict__ l2w, const float* __restrict__ l2b, const float* __restrict__ l2g,
                        const float* __restrict__ l2be, const float* __restrict__ l2m, const float* __restrict__ l2v,
                        const float* __restrict__ g2w, const float* __restrict__ g2b, const float* __restrict__ g2g,
                        const float* __restrict__ g2be, const float* __restrict__ g2m, const float* __restrict__ g2v,
                        bf16* __restrict__ W2f, float* __restrict__ b2sum) {
  int gid = blockIdx.x * blockDim.x + threadIdx.x;   // 1024*512
  int n = gid >> 9, k = gid & 511;
  float w;
  if (k < 256) { float s = l2g[n] * rsqrtf(l2v[n] + BN_EPS); w = l2w[(size_t)n * 256 + k] * s; }
  else { float s = g2g[n] * rsqrtf(g2v[n] + BN_EPS); w = g2w[(size_t)n * 256 + (k - 256)] * s; }
  W2f[frag_off(n, k, 64)] = (bf16)w;
  if (k == 0) {
    float sl = l2g[n] * rsqrtf(l2v[n] + BN_EPS), sg = g2g[n] * rsqrtf(g2v[n] + BN_EPS);
    b2sum[n] = sl * (l2b[n] - l2m[n]) + l2be[n] + sg * (g2b[n] - g2m[n]) + g2be[n];
  }
}

__global__ void prep_cwf(const float* __restrict__ cw, const float* __restrict__ cb, bf16* __restrict__ CWf) {
  int gid = blockIdx.x * blockDim.x + threadIdx.x;   // 1024*64
  int n = gid >> 6, kc = gid & 63;
  float v = (kc < 48) ? cw[(size_t)n * 48 + kc] : (kc == 48 ? cb[n] : 0.f);
  CWf[frag_off(n, kc, 64)] = (bf16)v;
}

__global__ void prep_f1f(const float* __restrict__ fw1, bf16* __restrict__ F1f) {
  int gid = blockIdx.x * blockDim.x + threadIdx.x;   // 256*2048
  int n = gid >> 11, k = gid & 2047;
  F1f[frag_off(n, k, 16)] = (bf16)fw1[(size_t)n * 2048 + k];
}

// ---------------- main fused kernel: e-build -> GEMM1 -> GEMM2 -> sigmoid combine -> r ----------------

__global__ __launch_bounds__(512, 2)
void fused_main(const float* __restrict__ name1, const float* __restrict__ type1, const float* __restrict__ coor1,
                const float* __restrict__ name2, const float* __restrict__ type2, const float* __restrict__ coor2,
                const bf16* __restrict__ W1f, const bf16* __restrict__ W2f, const bf16* __restrict__ CWf,
                const float* __restrict__ b1cat, const float* __restrict__ b2sum,
                bf16* __restrict__ r_ws) {
  const int t = blockIdx.y;
  const float* __restrict__ name = t ? name2 : name1;
  const float* __restrict__ typ  = t ? type2 : type1;
  const float* __restrict__ coor = t ? coor2 : coor1;
  const int b0 = blockIdx.x * 32;
  const int tid = threadIdx.x;
  const int lane = tid & 63;
  const int wv = tid >> 6;

  __shared__ bf16 E[32][1096];   // cols 0..1023: e = name+typ ; 1024..1087: [coor | 1 | 0pad]
  __shared__ bf16 H[32][520];    // relu(GEMM1) : [hL | hG]

  // ---- phase A: build E ----
  #pragma unroll
  for (int it = 0; it < 16; ++it) {
    int f = it * 512 + tid;
    int row = f >> 8, c4 = f & 255;
    float4 nv = *reinterpret_cast<const float4*>(name + (size_t)(b0 + row) * 1024 + c4 * 4);
    float4 tv = *reinterpret_cast<const float4*>(typ  + (size_t)(b0 + row) * 1024 + c4 * 4);
    bf16x4 ev;
    ev[0] = (bf16)(nv.x + tv.x); ev[1] = (bf16)(nv.y + tv.y);
    ev[2] = (bf16)(nv.z + tv.z); ev[3] = (bf16)(nv.w + tv.w);
    *reinterpret_cast<bf16x4*>(&E[row][c4 * 4]) = ev;
  }
  if (tid < 384) {
    int row = tid / 12, c4 = tid % 12;
    float4 cv = *reinterpret_cast<const float4*>(coor + (size_t)(b0 + row) * 48 + c4 * 4);
    bf16x4 ev;
    ev[0] = (bf16)cv.x; ev[1] = (bf16)cv.y; ev[2] = (bf16)cv.z; ev[3] = (bf16)cv.w;
    *reinterpret_cast<bf16x4*>(&E[row][1024 + c4 * 4]) = ev;
  }
  {
    int row = tid >> 4, kc = tid & 15;
    E[row][1072 + kc] = (kc == 0) ? (bf16)1.0f : (bf16)0.0f;   // the cb virtual column
  }
  __syncthreads();

  const int arow = lane & 15;
  const int kgrp = (lane >> 4) << 3;

  // ---- GEMM1: [32,1088] @ W1catT -> H[32,512], relu ----
  f32x4 acc1[2][4] = {};
  for (int ks = 0; ks < 34; ++ks) {
    bf16x8 a0 = *reinterpret_cast<const bf16x8*>(&E[arow][ks * 32 + kgrp]);
    bf16x8 a1 = *reinterpret_cast<const bf16x8*>(&E[16 + arow][ks * 32 + kgrp]);
    #pragma unroll
    for (int u = 0; u < 4; ++u) {
      int ntile = wv * 4 + u;
      bf16x8 b = *reinterpret_cast<const bf16x8*>(W1f + (((size_t)(ks * 32 + ntile)) << 9) + lane * 8);
      acc1[0][u] = __builtin_amdgcn_mfma_f32_16x16x32_bf16(a0, b, acc1[0][u], 0, 0, 0);
      acc1[1][u] = __builtin_amdgcn_mfma_f32_16x16x32_bf16(a1, b, acc1[1][u], 0, 0, 0);
    }
  }
  #pragma unroll
  for (int u = 0; u < 4; ++u) {
    int col = (wv * 4 + u) * 16 + arow;
    float bb = b1cat[col];
    #pragma unroll
    for (int m = 0; m < 2; ++m) {
      #pragma unroll
      for (int i = 0; i < 4; ++i) {
        int row = m * 16 + ((lane >> 4) << 2) + i;
        H[row][col] = (bf16)fmaxf(acc1[m][u][i] + bb, 0.f);
      }
    }
  }
  __syncthreads();

  // ---- GEMM2: [32,512] @ W2catT -> wei_pre[32,1024] ----
  f32x4 acc2[2][8] = {};
  for (int ks = 0; ks < 16; ++ks) {
    bf16x8 a0 = *reinterpret_cast<const bf16x8*>(&H[arow][ks * 32 + kgrp]);
    bf16x8 a1 = *reinterpret_cast<const bf16x8*>(&H[16 + arow][ks * 32 + kgrp]);
    #pragma unroll
    for (int u = 0; u < 8; ++u) {
      int ntile = wv * 8 + u;
      bf16x8 b = *reinterpret_cast<const bf16x8*>(W2f + (((size_t)(ks * 64 + ntile)) << 9) + lane * 8);
      acc2[0][u] = __builtin_amdgcn_mfma_f32_16x16x32_bf16(a0, b, acc2[0][u], 0, 0, 0);
      acc2[1][u] = __builtin_amdgcn_mfma_f32_16x16x32_bf16(a1, b, acc2[1][u], 0, 0, 0);
    }
  }

  // ---- combine: c-tile via 2-step MFMA, wei = sigmoid(.), t = 2e + 2*wei*(c-e) ----
  bf16x8 ca[2][2];
  ca[0][0] = *reinterpret_cast<const bf16x8*>(&E[arow][1024 + kgrp]);
  ca[0][1] = *reinterpret_cast<const bf16x8*>(&E[arow][1056 + kgrp]);
  ca[1][0] = *reinterpret_cast<const bf16x8*>(&E[16 + arow][1024 + kgrp]);
  ca[1][1] = *reinterpret_cast<const bf16x8*>(&E[16 + arow][1056 + kgrp]);
  #pragma unroll
  for (int u = 0; u < 8; ++u) {
    int ntile = wv * 8 + u;
    bf16x8 cb0 = *reinterpret_cast<const bf16x8*>(CWf + (((size_t)ntile) << 9) + lane * 8);
    bf16x8 cb1 = *reinterpret_cast<const bf16x8*>(CWf + (((size_t)(64 + ntile)) << 9) + lane * 8);
    f32x4 cc0 = {0.f, 0.f, 0.f, 0.f}, cc1 = {0.f, 0.f, 0.f, 0.f};
    cc0 = __builtin_amdgcn_mfma_f32_16x16x32_bf16(ca[0][0], cb0, cc0, 0, 0, 0);
    cc0 = __builtin_amdgcn_mfma_f32_16x16x32_bf16(ca[0][1], cb1, cc0, 0, 0, 0);
    cc1 = __builtin_amdgcn_mfma_f32_16x16x32_bf16(ca[1][0], cb0, cc1, 0, 0, 0);
    cc1 = __builtin_amdgcn_mfma_f32_16x16x32_bf16(ca[1][1], cb1, cc1, 0, 0, 0);
    int col = ntile * 16 + arow;
    float b2 = b2sum[col];
    #pragma unroll
    for (int m = 0; m < 2; ++m) {
      #pragma unroll
      for (int i = 0; i < 4; ++i) {
        int row = m * 16 + ((lane >> 4) << 2) + i;
        float x = acc2[m][u][i] + b2;
        float wei = 1.f / (1.f + __expf(-x));
        float e = (float)E[row][col];
        float cval = (m == 0) ? cc0[i] : cc1[i];
        float tvv = 2.f * e + 2.f * wei * (cval - e);
        r_ws[(size_t)(b0 + row) * 2048 + (size_t)t * 1024 + col] = (bf16)tvv;
      }
    }
  }
}

// ---------------- final kernel: out = sigmoid(relu(r@fw1T+fb1)@fw2T+fb2) ----------------

__global__ __launch_bounds__(512, 2)
void fused_final(const bf16* __restrict__ r_ws, const bf16* __restrict__ F1f,
                 const float* __restrict__ fb1, const float* __restrict__ fw2,
                 const float* __restrict__ fb2, float* __restrict__ out) {
  const int b0 = blockIdx.x * 64;
  const int tid = threadIdx.x;
  const int lane = tid & 63;
  const int wv = tid >> 6;

  __shared__ __align__(16) char smem[2 * 64 * 264 * 2];
  typedef bf16 RTrow[264];
  RTrow* RT0 = reinterpret_cast<RTrow*>(smem);
  RTrow* RT1 = reinterpret_cast<RTrow*>(smem + (size_t)64 * 264 * 2);
  typedef float H2row[260];
  H2row* H2 = reinterpret_cast<H2row*>(smem);   // overlays RT after k-loop

  auto stage = [&](int kc, RTrow* RT) {
    #pragma unroll
    for (int it = 0; it < 8; ++it) {
      int f = it * 512 + tid;
      int row = f >> 6, c4 = f & 63;
      *reinterpret_cast<bf16x4*>(&RT[row][c4 * 4]) =
        *reinterpret_cast<const bf16x4*>(r_ws + (size_t)(b0 + row) * 2048 + kc * 256 + c4 * 4);
    }
  };

  stage(0, RT0);
  __syncthreads();

  const int arow = lane & 15;
  const int kgrp = (lane >> 4) << 3;
  f32x4 acc[4][2] = {};
  for (int kc = 0; kc < 8; ++kc) {
    RTrow* cur = (kc & 1) ? RT1 : RT0;
    RTrow* nxt = (kc & 1) ? RT0 : RT1;
    if (kc < 7) stage(kc + 1, nxt);
    #pragma unroll
    for (int ks = 0; ks < 8; ++ks) {
      int ksg = kc * 8 + ks;
      bf16x8 a[4];
      #pragma unroll
      for (int m = 0; m < 4; ++m)
        a[m] = *reinterpret_cast<const bf16x8*>(&cur[m * 16 + arow][ks * 32 + kgrp]);
      #pragma unroll
      for (int u = 0; u < 2; ++u) {
        int ntile = wv * 2 + u;
        bf16x8 b = *reinterpret_cast<const bf16x8*>(F1f + (((size_t)(ksg * 16 + ntile)) << 9) + lane * 8);
        #pragma unroll
        for (int m = 0; m < 4; ++m)
          acc[m][u] = __builtin_amdgcn_mfma_f32_16x16x32_bf16(a[m], b, acc[m][u], 0, 0, 0);
      }
    }
    __syncthreads();
  }

  #pragma unroll
  for (int u = 0; u < 2; ++u) {
    int col = (wv * 2 + u) * 16 + arow;
    float bb = fb1[col];
    #pragma unroll
    for (int m = 0; m < 4; ++m) {
      #pragma unroll
      for (int i = 0; i < 4; ++i) {
        int row = m * 16 + ((lane >> 4) << 2) + i;
        H2[row][col] = fmaxf(acc[m][u][i] + bb, 0.f);
      }
    }
  }
  __syncthreads();

  int row = tid >> 3, sub = tid & 7;
  float p = 0.f;
  #pragma unroll
  for (int c = 0; c < 32; ++c) p += H2[row][sub * 32 + c] * fw2[sub * 32 + c];
  p += __shfl_xor(p, 1, 8);
  p += __shfl_xor(p, 2, 8);
  p += __shfl_xor(p, 4, 8);
  if (sub == 0) out[b0 + row] = 1.f / (1.f + __expf(-(p + fb2[0])));
}

// ---------------- launcher ----------------

extern "C" void kernel_launch(void* const* d_in, const int* in_sizes, int n_in,
                              void* d_out, int out_size, void* d_ws, size_t ws_size,
                              hipStream_t stream) {
  const float* name1 = (const float*)d_in[0];
  const float* type1 = (const float*)d_in[1];
  const float* coor1 = (const float*)d_in[2];
  const float* name2 = (const float*)d_in[3];
  const float* type2 = (const float*)d_in[4];
  const float* coor2 = (const float*)d_in[5];
  const float* cw    = (const float*)d_in[6];
  const float* cb    = (const float*)d_in[7];
  const float* l1w = (const float*)d_in[8];  const float* l1b = (const float*)d_in[9];
  const float* l1g = (const float*)d_in[10]; const float* l1be = (const float*)d_in[11];
  const float* l1m = (const float*)d_in[12]; const float* l1v = (const float*)d_in[13];
  const float* l2w = (const float*)d_in[14]; const float* l2b = (const float*)d_in[15];
  const float* l2g = (const float*)d_in[16]; const float* l2be = (const float*)d_in[17];
  const float* l2m = (const float*)d_in[18]; const float* l2v = (const float*)d_in[19];
  const float* g1w = (const float*)d_in[20]; const float* g1b = (const float*)d_in[21];
  const float* g1g = (const float*)d_in[22]; const float* g1be = (const float*)d_in[23];
  const float* g1m = (const float*)d_in[24]; const float* g1v = (const float*)d_in[25];
  const float* g2w = (const float*)d_in[26]; const float* g2b = (const float*)d_in[27];
  const float* g2g = (const float*)d_in[28]; const float* g2be = (const float*)d_in[29];
  const float* g2m = (const float*)d_in[30]; const float* g2v = (const float*)d_in[31];
  const float* fw1 = (const float*)d_in[32]; const float* fb1 = (const float*)d_in[33];
  const float* fw2 = (const float*)d_in[34]; const float* fb2 = (const float*)d_in[35];

  char* ws = (char*)d_ws;
  bf16*  W1f   = (bf16*)(ws + 0);          // 512*1088 bf16  = 1,114,112 B
  bf16*  W2f   = (bf16*)(ws + 1114112);    // 1024*512 bf16  = 1,048,576 B
  bf16*  CWf   = (bf16*)(ws + 2162688);    // 1024*64  bf16  =   131,072 B
  bf16*  F1f   = (bf16*)(ws + 2293760);    // 256*2048 bf16  = 1,048,576 B
  float* b1cat = (float*)(ws + 3342336);   // 512 f32
  float* b2sum = (float*)(ws + 3344384);   // 1024 f32
  bf16*  r_ws  = (bf16*)(ws + 3407872);    // 16384*2048 bf16 = 67,108,864 B

  prep_w1main<<<2048, 256, 0, stream>>>(l1w, l1g, l1v, g1w, g1g, g1v, W1f);
  prep_w1tail<<<128, 256, 0, stream>>>(l1w, l1b, l1g, l1be, l1m, l1v,
                                       g1w, g1b, g1g, g1be, g1m, g1v, cw, cb, W1f, b1cat);
  prep_w2<<<2048, 256, 0, stream>>>(l2w, l2b, l2g, l2be, l2m, l2v,
                                    g2w, g2b, g2g, g2be, g2m, g2v, W2f, b2sum);
  prep_cwf<<<256, 256, 0, stream>>>(cw, cb, CWf);
  prep_f1f<<<2048, 256, 0, stream>>>(fw1, F1f);

  fused_main<<<dim3(512, 2), 512, 0, stream>>>(name1, type1, coor1, name2, type2, coor2,
                                               W1f, W2f, CWf, b1cat, b2sum, r_ws);
  fused_final<<<256, 512, 0, stream>>>(r_ws, F1f, fb1, fw2, fb2, (float*)d_out);
}

// Round 2
// 355.918 us; speedup vs baseline: 1.0535x; 1.0535x over previous
//
#include <hip/hip_runtime.h>

typedef __bf16 bf16;
typedef __bf16 bf16x8 __attribute__((ext_vector_type(8)));
typedef __bf16 bf16x4 __attribute__((ext_vector_type(4)));
typedef float  f32x4  __attribute__((ext_vector_type(4)));

#define BN_EPS 1e-5f

// Fragment-linear offset for MFMA B-operand matrix [N][K] (16x16x32 tiles):
// tile = (k/32)*ntiles + n/16 ; within tile: lane = ((k%32)/8)*16 + n%16, elem = k%8
__device__ __host__ __forceinline__ size_t frag_off(int n, int k, int ntiles) {
  return ((size_t)((k >> 5) * ntiles + (n >> 4)) << 9)
       + (size_t)((((k >> 3) & 3) << 4) + (n & 15)) * 8 + (k & 7);
}

// ---------------- prep kernels: fold BN, cast to bf16, swizzle to fragment layout ----------------

__global__ void prep_w1main(const float* __restrict__ l1w, const float* __restrict__ l1g, const float* __restrict__ l1v,
                            const float* __restrict__ g1w, const float* __restrict__ g1g, const float* __restrict__ g1v,
                            bf16* __restrict__ W1f) {
  int gid = blockIdx.x * blockDim.x + threadIdx.x;   // 512*1024
  int n = gid >> 10, k = gid & 1023;
  float s, w;
  if (n < 256) { s = l1g[n] * rsqrtf(l1v[n] + BN_EPS); w = l1w[(size_t)n * 1024 + k]; }
  else { int nn = n - 256; s = g1g[nn] * rsqrtf(g1v[nn] + BN_EPS); w = g1w[(size_t)nn * 1024 + k]; }
  W1f[frag_off(n, k, 32)] = (bf16)(w * s);
}

// tail columns 1024..1087 of W1cat = (s*W1) @ [cw | cb | 0], plus b1cat
__global__ void prep_w1tail(const float* __restrict__ l1w, const float* __restrict__ l1b, const float* __restrict__ l1g,
                            const float* __restrict__ l1be, const float* __restrict__ l1m, const float* __restrict__ l1v,
                            const float* __restrict__ g1w, const float* __restrict__ g1b, const float* __restrict__ g1g,
                            const float* __restrict__ g1be, const float* __restrict__ g1m, const float* __restrict__ g1v,
                            const float* __restrict__ cw, const float* __restrict__ cb,
                            bf16* __restrict__ W1f, float* __restrict__ b1cat) {
  int gid = blockIdx.x * blockDim.x + threadIdx.x;   // 512*64
  int n = gid >> 6, kc = gid & 63;
  const float* wrow; float s, bb, mm, be;
  if (n < 256) { s = l1g[n] * rsqrtf(l1v[n] + BN_EPS); wrow = l1w + (size_t)n * 1024;
                 bb = l1b[n]; mm = l1m[n]; be = l1be[n]; }
  else { int nn = n - 256; s = g1g[nn] * rsqrtf(g1v[nn] + BN_EPS); wrow = g1w + (size_t)nn * 1024;
         bb = g1b[nn]; mm = g1m[nn]; be = g1be[nn]; }
  float val = 0.f;
  if (kc < 49) {
    for (int j = 0; j < 1024; ++j) {
      float cv = (kc < 48) ? cw[(size_t)j * 48 + kc] : cb[j];
      val += wrow[j] * cv;
    }
    val *= s;
  }
  W1f[frag_off(n, 1024 + kc, 32)] = (bf16)val;
  if (kc == 0) b1cat[n] = s * (bb - mm) + be;
}

__global__ void prep_w2(const float* __restrict__ l2w, const float* __restrict__ l2b, const float* __restrict__ l2g,
                        const float* __restrict__ l2be, const float* __restrict__ l2m, const float* __restrict__ l2v,
                        const float* __restrict__ g2w, const float* __restrict__ g2b, const float* __restrict__ g2g,
                        const float* __restrict__ g2be, const float* __restrict__ g2m, const float* __restrict__ g2v,
                        bf16* __restrict__ W2f, float* __restrict__ b2sum) {
  int gid = blockIdx.x * blockDim.x + threadIdx.x;   // 1024*512
  int n = gid >> 9, k = gid & 511;
  float w;
  if (k < 256) { float s = l2g[n] * rsqrtf(l2v[n] + BN_EPS); w = l2w[(size_t)n * 256 + k] * s; }
  else { float s = g2g[n] * rsqrtf(g2v[n] + BN_EPS); w = g2w[(size_t)n * 256 + (k - 256)] * s; }
  W2f[frag_off(n, k, 64)] = (bf16)w;
  if (k == 0) {
    float sl = l2g[n] * rsqrtf(l2v[n] + BN_EPS), sg = g2g[n] * rsqrtf(g2v[n] + BN_EPS);
    b2sum[n] = sl * (l2b[n] - l2m[n]) + l2be[n] + sg * (g2b[n] - g2m[n]) + g2be[n];
  }
}

__global__ void prep_cwf(const float* __restrict__ cw, const float* __restrict__ cb, bf16* __restrict__ CWf) {
  int gid = blockIdx.x * blockDim.x + threadIdx.x;   // 1024*64
  int n = gid >> 6, kc = gid & 63;
  float v = (kc < 48) ? cw[(size_t)n * 48 + kc] : (kc == 48 ? cb[n] : 0.f);
  CWf[frag_off(n, kc, 64)] = (bf16)v;
}

__global__ void prep_f1f(const float* __restrict__ fw1, bf16* __restrict__ F1f) {
  int gid = blockIdx.x * blockDim.x + threadIdx.x;   // 256*2048
  int n = gid >> 11, k = gid & 2047;
  F1f[frag_off(n, k, 16)] = (bf16)fw1[(size_t)n * 2048 + k];
}

// ---------------- main fused kernel: pipelined e-stream -> GEMM1 -> GEMM2 -> combine -> r ----------------

__global__ __launch_bounds__(512, 2)
void fused_main(const float* __restrict__ name1, const float* __restrict__ type1, const float* __restrict__ coor1,
                const float* __restrict__ name2, const float* __restrict__ type2, const float* __restrict__ coor2,
                const bf16* __restrict__ W1f, const bf16* __restrict__ W2f, const bf16* __restrict__ CWf,
                const float* __restrict__ b1cat, const float* __restrict__ b2sum,
                bf16* __restrict__ r_ws) {
  const int t = blockIdx.y;
  const float* __restrict__ name = t ? name2 : name1;
  const float* __restrict__ typ  = t ? type2 : type1;
  const float* __restrict__ coor = t ? coor2 : coor1;
  const int b0 = blockIdx.x * 32;
  const int tid = threadIdx.x;
  const int lane = tid & 63;
  const int wv = tid >> 6;
  const int lrow = tid >> 4, lg = tid & 15;   // staging map: 32 rows x 16 float4-cols

  __shared__ bf16 E[32][1096];   // cols 0..1023: e = name+typ ; 1024..1087: [coor | 1 | 0pad]
  __shared__ bf16 H[32][520];    // relu(GEMM1) : [hL | hG]

  const int arow = lane & 15;
  const int kgrp = (lane >> 4) << 3;

  // ---- GEMM1 with software-pipelined E staging (17 slices of 64 k) ----
  float4 nA, tA, nB, tB;
  auto load_slice = [&](int j, float4& nv, float4& tv) {
    if (j < 16) {
      nv = *reinterpret_cast<const float4*>(name + (size_t)(b0 + lrow) * 1024 + j * 64 + lg * 4);
      tv = *reinterpret_cast<const float4*>(typ  + (size_t)(b0 + lrow) * 1024 + j * 64 + lg * 4);
    } else {  // tail slice: [coor(48) | 1 | 0...]
      tv = make_float4(0.f, 0.f, 0.f, 0.f);
      if (lg < 12)       nv = *reinterpret_cast<const float4*>(coor + (size_t)(b0 + lrow) * 48 + lg * 4);
      else if (lg == 12) nv = make_float4(1.f, 0.f, 0.f, 0.f);
      else               nv = make_float4(0.f, 0.f, 0.f, 0.f);
    }
  };

  load_slice(0, nA, tA);
  load_slice(1, nB, tB);

  f32x4 acc1[2][4] = {};
  #pragma unroll 1
  for (int i = 0; i < 17; ++i) {
    {  // write slice i (regs held in A) to its private LDS region
      bf16x4 ev;
      ev[0] = (bf16)(nA.x + tA.x); ev[1] = (bf16)(nA.y + tA.y);
      ev[2] = (bf16)(nA.z + tA.z); ev[3] = (bf16)(nA.w + tA.w);
      *reinterpret_cast<bf16x4*>(&E[lrow][i * 64 + lg * 4]) = ev;
    }
    if (i + 2 < 17) load_slice(i + 2, nA, tA);   // keep 2 slices of HBM loads in flight
    __syncthreads();                             // slice i visible; disjoint regions -> 1 barrier/slice
    #pragma unroll
    for (int ks2 = 0; ks2 < 2; ++ks2) {
      int kk = i * 2 + ks2;
      bf16x8 a0 = *reinterpret_cast<const bf16x8*>(&E[arow][kk * 32 + kgrp]);
      bf16x8 a1 = *reinterpret_cast<const bf16x8*>(&E[16 + arow][kk * 32 + kgrp]);
      #pragma unroll
      for (int u = 0; u < 4; ++u) {
        bf16x8 b = *reinterpret_cast<const bf16x8*>(W1f + (((size_t)(kk * 32 + wv * 4 + u)) << 9) + lane * 8);
        acc1[0][u] = __builtin_amdgcn_mfma_f32_16x16x32_bf16(a0, b, acc1[0][u], 0, 0, 0);
        acc1[1][u] = __builtin_amdgcn_mfma_f32_16x16x32_bf16(a1, b, acc1[1][u], 0, 0, 0);
      }
    }
    float4 sn = nA, st = tA; nA = nB; tA = tB; nB = sn; tB = st;  // rotate pipeline regs
  }

  #pragma unroll
  for (int u = 0; u < 4; ++u) {
    int col = (wv * 4 + u) * 16 + arow;
    float bb = b1cat[col];
    #pragma unroll
    for (int m = 0; m < 2; ++m) {
      #pragma unroll
      for (int i = 0; i < 4; ++i) {
        int row = m * 16 + ((lane >> 4) << 2) + i;
        H[row][col] = (bf16)fmaxf(acc1[m][u][i] + bb, 0.f);
      }
    }
  }
  __syncthreads();

  // ---- GEMM2: [32,512] @ W2catT -> wei_pre[32,1024] ----
  f32x4 acc2[2][8] = {};
  for (int ks = 0; ks < 16; ++ks) {
    bf16x8 a0 = *reinterpret_cast<const bf16x8*>(&H[arow][ks * 32 + kgrp]);
    bf16x8 a1 = *reinterpret_cast<const bf16x8*>(&H[16 + arow][ks * 32 + kgrp]);
    #pragma unroll
    for (int u = 0; u < 8; ++u) {
      int ntile = wv * 8 + u;
      bf16x8 b = *reinterpret_cast<const bf16x8*>(W2f + (((size_t)(ks * 64 + ntile)) << 9) + lane * 8);
      acc2[0][u] = __builtin_amdgcn_mfma_f32_16x16x32_bf16(a0, b, acc2[0][u], 0, 0, 0);
      acc2[1][u] = __builtin_amdgcn_mfma_f32_16x16x32_bf16(a1, b, acc2[1][u], 0, 0, 0);
    }
  }

  // ---- combine: c via 2-step MFMA, wei = sigmoid, r = 2e + 2*wei*(c-e) written IN PLACE into E ----
  // lane-bijective: each (row,col) is read (e) and written (r) by the same lane -> no barrier needed
  bf16x8 ca[2][2];
  ca[0][0] = *reinterpret_cast<const bf16x8*>(&E[arow][1024 + kgrp]);
  ca[0][1] = *reinterpret_cast<const bf16x8*>(&E[arow][1056 + kgrp]);
  ca[1][0] = *reinterpret_cast<const bf16x8*>(&E[16 + arow][1024 + kgrp]);
  ca[1][1] = *reinterpret_cast<const bf16x8*>(&E[16 + arow][1056 + kgrp]);
  #pragma unroll
  for (int u = 0; u < 8; ++u) {
    int ntile = wv * 8 + u;
    bf16x8 cb0 = *reinterpret_cast<const bf16x8*>(CWf + (((size_t)ntile) << 9) + lane * 8);
    bf16x8 cb1 = *reinterpret_cast<const bf16x8*>(CWf + (((size_t)(64 + ntile)) << 9) + lane * 8);
    f32x4 cc0 = {0.f, 0.f, 0.f, 0.f}, cc1 = {0.f, 0.f, 0.f, 0.f};
    cc0 = __builtin_amdgcn_mfma_f32_16x16x32_bf16(ca[0][0], cb0, cc0, 0, 0, 0);
    cc0 = __builtin_amdgcn_mfma_f32_16x16x32_bf16(ca[0][1], cb1, cc0, 0, 0, 0);
    cc1 = __builtin_amdgcn_mfma_f32_16x16x32_bf16(ca[1][0], cb0, cc1, 0, 0, 0);
    cc1 = __builtin_amdgcn_mfma_f32_16x16x32_bf16(ca[1][1], cb1, cc1, 0, 0, 0);
    int col = ntile * 16 + arow;
    float b2 = b2sum[col];
    #pragma unroll
    for (int m = 0; m < 2; ++m) {
      #pragma unroll
      for (int i = 0; i < 4; ++i) {
        int row = m * 16 + ((lane >> 4) << 2) + i;
        float x = acc2[m][u][i] + b2;
        float wei = 1.f / (1.f + __expf(-x));
        float e = (float)E[row][col];
        float cval = (m == 0) ? cc0[i] : cc1[i];
        E[row][col] = (bf16)(2.f * e + 2.f * wei * (cval - e));
      }
    }
  }
  __syncthreads();

  // ---- coalesced r writeout: bf16x8 per lane ----
  #pragma unroll
  for (int it = 0; it < 8; ++it) {
    int f = it * 512 + tid;
    int row = f >> 7, g = f & 127;
    *reinterpret_cast<bf16x8*>(r_ws + (size_t)(b0 + row) * 2048 + (size_t)t * 1024 + g * 8) =
      *reinterpret_cast<const bf16x8*>(&E[row][g * 8]);
  }
}

// ---------------- final kernel: out = sigmoid(relu(r@fw1T+fb1)@fw2T+fb2) ----------------

__global__ __launch_bounds__(512, 2)
void fused_final(const bf16* __restrict__ r_ws, const bf16* __restrict__ F1f,
                 const float* __restrict__ fb1, const float* __restrict__ fw2,
                 const float* __restrict__ fb2, float* __restrict__ out) {
  const int b0 = blockIdx.x * 32;
  const int tid = threadIdx.x;
  const int lane = tid & 63;
  const int wv = tid >> 6;

  __shared__ __align__(16) char smem[2 * 32 * 264 * 2];   // 33,792 B -> 4 blocks/CU
  typedef bf16 RTrow[264];
  RTrow* RT0 = reinterpret_cast<RTrow*>(smem);
  RTrow* RT1 = reinterpret_cast<RTrow*>(smem + 32 * 264 * 2);
  typedef float H2row[260];
  H2row* H2 = reinterpret_cast<H2row*>(smem);   // overlays RT after k-loop (33,280 B)

  const int srow0 = tid >> 5, sg0 = tid & 31;   // staging map: 2 x (16 rows x 32 groups)

  bf16x8 s0, s1;
  auto stage_load = [&](int kc) {
    s0 = *reinterpret_cast<const bf16x8*>(r_ws + (size_t)(b0 + srow0) * 2048 + kc * 256 + sg0 * 8);
    s1 = *reinterpret_cast<const bf16x8*>(r_ws + (size_t)(b0 + 16 + srow0) * 2048 + kc * 256 + sg0 * 8);
  };
  auto stage_write = [&](RTrow* RT) {
    *reinterpret_cast<bf16x8*>(&RT[srow0][sg0 * 8]) = s0;
    *reinterpret_cast<bf16x8*>(&RT[16 + srow0][sg0 * 8]) = s1;
  };

  stage_load(0); stage_write(RT0);
  __syncthreads();

  const int arow = lane & 15;
  const int kgrp = (lane >> 4) << 3;
  f32x4 acc[2][2] = {};
  #pragma unroll 1
  for (int kc = 0; kc < 8; ++kc) {
    RTrow* cur = (kc & 1) ? RT1 : RT0;
    RTrow* nxt = (kc & 1) ? RT0 : RT1;
    if (kc < 7) stage_load(kc + 1);          // issue HBM loads early (T14)
    #pragma unroll
    for (int ks = 0; ks < 8; ++ks) {
      int ksg = kc * 8 + ks;
      bf16x8 a0 = *reinterpret_cast<const bf16x8*>(&cur[arow][ks * 32 + kgrp]);
      bf16x8 a1 = *reinterpret_cast<const bf16x8*>(&cur[16 + arow][ks * 32 + kgrp]);
      #pragma unroll
      for (int u = 0; u < 2; ++u) {
        bf16x8 b = *reinterpret_cast<const bf16x8*>(F1f + (((size_t)(ksg * 16 + wv * 2 + u)) << 9) + lane * 8);
        acc[0][u] = __builtin_amdgcn_mfma_f32_16x16x32_bf16(a0, b, acc[0][u], 0, 0, 0);
        acc[1][u] = __builtin_amdgcn_mfma_f32_16x16x32_bf16(a1, b, acc[1][u], 0, 0, 0);
      }
    }
    if (kc < 7) stage_write(nxt);            // ds_write after MFMAs; loads were in flight
    __syncthreads();
  }

  #pragma unroll
  for (int u = 0; u < 2; ++u) {
    int col = (wv * 2 + u) * 16 + arow;
    float bb = fb1[col];
    #pragma unroll
    for (int m = 0; m < 2; ++m) {
      #pragma unroll
      for (int i = 0; i < 4; ++i) {
        int row = m * 16 + ((lane >> 4) << 2) + i;
        H2[row][col] = fmaxf(acc[m][u][i] + bb, 0.f);
      }
    }
  }
  __syncthreads();

  int row = tid >> 4, sub = tid & 15;
  float p = 0.f;
  #pragma unroll
  for (int c = 0; c < 16; ++c) p += H2[row][sub * 16 + c] * fw2[sub * 16 + c];
  p += __shfl_xor(p, 1, 16);
  p += __shfl_xor(p, 2, 16);
  p += __shfl_xor(p, 4, 16);
  p += __shfl_xor(p, 8, 16);
  if (sub == 0) out[b0 + row] = 1.f / (1.f + __expf(-(p + fb2[0])));
}

// ---------------- launcher ----------------

extern "C" void kernel_launch(void* const* d_in, const int* in_sizes, int n_in,
                              void* d_out, int out_size, void* d_ws, size_t ws_size,
                              hipStream_t stream) {
  const float* name1 = (const float*)d_in[0];
  const float* type1 = (const float*)d_in[1];
  const float* coor1 = (const float*)d_in[2];
  const float* name2 = (const float*)d_in[3];
  const float* type2 = (const float*)d_in[4];
  const float* coor2 = (const float*)d_in[5];
  const float* cw    = (const float*)d_in[6];
  const float* cb    = (const float*)d_in[7];
  const float* l1w = (const float*)d_in[8];  const float* l1b = (const float*)d_in[9];
  const float* l1g = (const float*)d_in[10]; const float* l1be = (const float*)d_in[11];
  const float* l1m = (const float*)d_in[12]; const float* l1v = (const float*)d_in[13];
  const float* l2w = (const float*)d_in[14]; const float* l2b = (const float*)d_in[15];
  const float* l2g = (const float*)d_in[16]; const float* l2be = (const float*)d_in[17];
  const float* l2m = (const float*)d_in[18]; const float* l2v = (const float*)d_in[19];
  const float* g1w = (const float*)d_in[20]; const float* g1b = (const float*)d_in[21];
  const float* g1g = (const float*)d_in[22]; const float* g1be = (const float*)d_in[23];
  const float* g1m = (const float*)d_in[24]; const float* g1v = (const float*)d_in[25];
  const float* g2w = (const float*)d_in[26]; const float* g2b = (const float*)d_in[27];
  const float* g2g = (const float*)d_in[28]; const float* g2be = (const float*)d_in[29];
  const float* g2m = (const float*)d_in[30]; const float* g2v = (const float*)d_in[31];
  const float* fw1 = (const float*)d_in[32]; const float* fb1 = (const float*)d_in[33];
  const float* fw2 = (const float*)d_in[34]; const float* fb2 = (const float*)d_in[35];

  char* ws = (char*)d_ws;
  bf16*  W1f   = (bf16*)(ws + 0);          // 512*1088 bf16  = 1,114,112 B
  bf16*  W2f   = (bf16*)(ws + 1114112);    // 1024*512 bf16  = 1,048,576 B
  bf16*  CWf   = (bf16*)(ws + 2162688);    // 1024*64  bf16  =   131,072 B
  bf16*  F1f   = (bf16*)(ws + 2293760);    // 256*2048 bf16  = 1,048,576 B
  float* b1cat = (float*)(ws + 3342336);   // 512 f32
  float* b2sum = (float*)(ws + 3344384);   // 1024 f32
  bf16*  r_ws  = (bf16*)(ws + 3407872);    // 16384*2048 bf16 = 67,108,864 B

  prep_w1main<<<2048, 256, 0, stream>>>(l1w, l1g, l1v, g1w, g1g, g1v, W1f);
  prep_w1tail<<<128, 256, 0, stream>>>(l1w, l1b, l1g, l1be, l1m, l1v,
                                       g1w, g1b, g1g, g1be, g1m, g1v, cw, cb, W1f, b1cat);
  prep_w2<<<2048, 256, 0, stream>>>(l2w, l2b, l2g, l2be, l2m, l2v,
                                    g2w, g2b, g2g, g2be, g2m, g2v, W2f, b2sum);
  prep_cwf<<<256, 256, 0, stream>>>(cw, cb, CWf);
  prep_f1f<<<2048, 256, 0, stream>>>(fw1, F1f);

  fused_main<<<dim3(512, 2), 512, 0, stream>>>(name1, type1, coor1, name2, type2, coor2,
                                               W1f, W2f, CWf, b1cat, b2sum, r_ws);
  fused_final<<<512, 512, 0, stream>>>(r_ws, F1f, fb1, fw2, fb2, (float*)d_out);
}